// Round 1
// baseline (615.870 us; speedup 1.0000x reference)
//
#include <hip/hip_runtime.h>

// DiffusionConvolution: out = X + M @ X,
//   M = th10*Wp1 + th11*WTp1 + th20*Wp2 + th21*WTp2   (Wp0 = WTp0 = I folded
//   into self_scale = 1 + th00 + th01).
//
// R6 structural rewrite ("row-per-wave register streaming"):
//  - The 4 N*N matrices are SINGLE-USE: stream them global->register->FMA.
//    No LDS staging, no barriers in the main loop (the old kernel drained
//    vmcnt(0) at 2 barriers per 128-k tile -> latency-bound at ~2.7 TB/s).
//  - One output row per wave (4096 waves = 16/CU). Lane l owns k = k0+l+64j;
//    matrix loads are coalesced b32 (256B/instr, full lines), prefetched one
//    256-k step ahead into a double register buffer (~4KB in flight per wave).
//  - Only X (256KB, reused by all blocks) is in LDS: 4 phases x 64KB,
//    2 barriers per phase = 8 barriers total per block.
//    Swizzle: quad q of row k at byte k*64 + ((q ^ ((k>>1)&3))<<4) ->
//    the wave's 64 lanes cover all 8 16B bank slots -> conflict-free b128.
//  - Epilogue: 64-lane butterfly reduce; lane 0 writes self_scale*X[r]+acc.
//    Kills the init kernel and all atomics: ONE kernel, one graph node.
// Roofline: 268 MB @ ~6.3 TB/s ~= 43 us for this kernel.

constexpr int N  = 4096;
constexpr int F  = 16;
constexpr int TPB     = 512;     // 8 waves per block
constexpr int RPB     = 8;       // rows per block (1 per wave)
constexpr int PHASE_K = 1024;    // X rows resident per LDS phase (64 KB)

__global__ __launch_bounds__(TPB, 4) void diffconv_kernel(
    const float* __restrict__ X,      // [N, F]
    const float* __restrict__ theta,  // [3, 2]
    const float* __restrict__ Wp,     // [3, N, N]
    const float* __restrict__ WTp,    // [3, N, N]
    float* __restrict__ out)          // [N, F]
{
    __shared__ float x_lds[PHASE_K * F];   // 64 KB, XOR-swizzled quads

    const int tid  = threadIdx.x;
    const int lane = tid & 63;
    const int wave = tid >> 6;
    const int r    = blockIdx.x * RPB + wave;

    const float th00 = theta[0], th01 = theta[1];
    const float th10 = theta[2], th11 = theta[3];
    const float th20 = theta[4], th21 = theta[5];

    const float* __restrict__ Wp1  = Wp  + (size_t)N * N;
    const float* __restrict__ Wp2  = Wp  + 2 * (size_t)N * N;
    const float* __restrict__ WTp1 = WTp + (size_t)N * N;
    const float* __restrict__ WTp2 = WTp + 2 * (size_t)N * N;

    const size_t rowb = (size_t)r * N;

    float acc[16];
#pragma unroll
    for (int f = 0; f < 16; ++f) acc[f] = 0.0f;

    float bufA[4][4], bufB[4][4];   // [matrix][sub-k j], double-buffered

    // Issue one 256-k step's matrix loads (nontemporal: zero-reuse streams).
    auto prefetch = [&](float (&dst)[4][4], int k0) {
#pragma unroll
        for (int j = 0; j < 4; ++j) {
            const size_t o = rowb + (size_t)(k0 + j * 64 + lane);
            dst[0][j] = __builtin_nontemporal_load(Wp1  + o);
            dst[1][j] = __builtin_nontemporal_load(WTp1 + o);
            dst[2][j] = __builtin_nontemporal_load(Wp2  + o);
            dst[3][j] = __builtin_nontemporal_load(WTp2 + o);
        }
    };

    // Consume one step: combine 4 streams -> c, FMA against X row from LDS.
    auto compute = [&](float (&cur)[4][4], int k0) {
#pragma unroll
        for (int j = 0; j < 4; ++j) {
            const float c = th10 * cur[0][j] + th11 * cur[1][j]
                          + th20 * cur[2][j] + th21 * cur[3][j];
            const int krel = (k0 & (PHASE_K - 1)) + j * 64 + lane;
            const int base = krel << 4;          // float index of row
            const int sw   = (krel >> 1) & 3;    // quad XOR swizzle
#pragma unroll
            for (int q = 0; q < 4; ++q) {
                const float4 xq = *(const float4*)&x_lds[base + ((q ^ sw) << 2)];
                acc[4*q+0] = fmaf(c, xq.x, acc[4*q+0]);
                acc[4*q+1] = fmaf(c, xq.y, acc[4*q+1]);
                acc[4*q+2] = fmaf(c, xq.z, acc[4*q+2]);
                acc[4*q+3] = fmaf(c, xq.w, acc[4*q+3]);
            }
        }
    };

    prefetch(bufA, 0);   // overlaps with phase-0 staging

    for (int p = 0; p < 4; ++p) {
        __syncthreads();   // all waves done reading previous phase
        // Stage phase p: X rows [p*1024, p*1024+1024) -> swizzled LDS.
#pragma unroll
        for (int h = 0; h < 2; ++h) {
            const int krel = tid + h * 512;
            const float4* src =
                (const float4*)(X + (size_t)(p * PHASE_K + krel) * F);
            const int base = krel << 4;
            const int sw   = (krel >> 1) & 3;
#pragma unroll
            for (int q = 0; q < 4; ++q)
                *(float4*)&x_lds[base + ((q ^ sw) << 2)] = src[q];
        }
        __syncthreads();

        const int k0 = p * PHASE_K;
        // 4 steps of 256 k; prefetch next step before consuming current.
        prefetch(bufB, k0 + 256);
        compute(bufA, k0);
        prefetch(bufA, k0 + 512);
        compute(bufB, k0 + 256);
        prefetch(bufB, k0 + 768);
        compute(bufA, k0 + 512);
        if (p < 3) prefetch(bufA, k0 + 1024);   // crosses into next phase
        compute(bufB, k0 + 768);
    }

    // Butterfly-reduce the per-lane k-partials across the 64 lanes.
#pragma unroll
    for (int mask = 1; mask < 64; mask <<= 1)
#pragma unroll
        for (int f = 0; f < 16; ++f)
            acc[f] += __shfl_xor(acc[f], mask, 64);

    if (lane == 0) {
        const float self_scale = 1.0f + th00 + th01;
        const float4* xp = (const float4*)(X + (size_t)r * F);
        float4*       op = (float4*)(out + (size_t)r * F);
#pragma unroll
        for (int q = 0; q < 4; ++q) {
            const float4 xv = xp[q];
            float4 ov;
            ov.x = self_scale * xv.x + acc[4*q+0];
            ov.y = self_scale * xv.y + acc[4*q+1];
            ov.z = self_scale * xv.z + acc[4*q+2];
            ov.w = self_scale * xv.w + acc[4*q+3];
            op[q] = ov;
        }
    }
}

extern "C" void kernel_launch(void* const* d_in, const int* in_sizes, int n_in,
                              void* d_out, int out_size, void* d_ws, size_t ws_size,
                              hipStream_t stream) {
    const float* X     = (const float*)d_in[0];
    const float* theta = (const float*)d_in[1];
    const float* Wp    = (const float*)d_in[2];
    const float* WTp   = (const float*)d_in[3];
    float* out = (float*)d_out;

    diffconv_kernel<<<N / RPB, TPB, 0, stream>>>(X, theta, Wp, WTp, out);
}

// Round 2
// 443.326 us; speedup vs baseline: 1.3892x; 1.3892x over previous
//
#include <hip/hip_runtime.h>

// DiffusionConvolution: out = X + M @ X,
//   M = th10*Wp1 + th11*WTp1 + th20*Wp2 + th21*WTp2   (Wp0 = WTp0 = I folded
//   into self_scale = 1 + th00 + th01).
//
// R7 = R6 structure (row-per-wave register streaming, X-in-LDS, zero
// main-loop barriers) with the SPILL fixed:
//  - R6 spilled its whole pipeline to scratch (WRITE_SIZE 761 MB, VGPR=64,
//    VALUBusy 0.08%): __launch_bounds__(512,4) squeezed the allocator and the
//    byref-lambda arrays lost SROA. Scratch round-trips serialized everything.
//  - Fix: pipeline state is NAMED float4 registers (pa*/pb*/acc*), code
//    expanded via macros; launch bounds relaxed to (512) (cap 256 VGPR).
//    LDS (64 KB) already pins 2 blocks/CU = 16 waves/CU; VGPR<=128 suffices.
//  - Matrices are single-use: global->register (nontemporal b32, 256 B/instr
//    coalesced), one 256-k step prefetched ahead (~4 KB in flight per wave,
//    16 waves/CU -> ~64 KB/CU >> 9 KB latency-BW product).
//  - X (256 KB, reused by every block) lives in LDS, 4 phases x 64 KB,
//    2 barriers per phase = 8 barriers total. Quad-XOR swizzle
//    (byte k*64 + ((q ^ ((k>>1)&3))<<4)) -> minimal 8-round b128 reads.
//  - Epilogue: butterfly reduce, lane 0 writes self_scale*X[r]+acc.
//    One kernel, no atomics, no init pass.
// Roofline: 268 MB @ ~6.3 TB/s ~= 43 us for this kernel.

constexpr int N  = 4096;
constexpr int F  = 16;
constexpr int TPB     = 512;     // 8 waves per block
constexpr int RPB     = 8;       // rows per block (1 per wave)
constexpr int PHASE_K = 1024;    // X rows resident per LDS phase (64 KB)

// Load one 256-k step of the 4 matrix streams into 4 named float4 regs.
// Component e of P holds k = K0 + 64*e + lane.
#define PREFETCH(P0, P1, P2, P3, K0) do {                                   \
    const size_t o_ = rowb + (size_t)(K0) + (size_t)lane;                   \
    P0.x = __builtin_nontemporal_load(Wp1  + o_);                           \
    P0.y = __builtin_nontemporal_load(Wp1  + o_ + 64);                      \
    P0.z = __builtin_nontemporal_load(Wp1  + o_ + 128);                     \
    P0.w = __builtin_nontemporal_load(Wp1  + o_ + 192);                     \
    P1.x = __builtin_nontemporal_load(WTp1 + o_);                           \
    P1.y = __builtin_nontemporal_load(WTp1 + o_ + 64);                      \
    P1.z = __builtin_nontemporal_load(WTp1 + o_ + 128);                     \
    P1.w = __builtin_nontemporal_load(WTp1 + o_ + 192);                     \
    P2.x = __builtin_nontemporal_load(Wp2  + o_);                           \
    P2.y = __builtin_nontemporal_load(Wp2  + o_ + 64);                      \
    P2.z = __builtin_nontemporal_load(Wp2  + o_ + 128);                     \
    P2.w = __builtin_nontemporal_load(Wp2  + o_ + 192);                     \
    P3.x = __builtin_nontemporal_load(WTp2 + o_);                           \
    P3.y = __builtin_nontemporal_load(WTp2 + o_ + 64);                      \
    P3.z = __builtin_nontemporal_load(WTp2 + o_ + 128);                     \
    P3.w = __builtin_nontemporal_load(WTp2 + o_ + 192);                     \
} while (0)

// One k element: fuse 4 streams -> coefficient c, FMA against X row KREL.
#define STEP_J(AX, BX, CX, DX, KREL) do {                                   \
    const float c_ = th10*(AX) + th11*(BX) + th20*(CX) + th21*(DX);         \
    const int base_ = (KREL) << 4;                                          \
    const int sw_   = ((KREL) >> 1) & 3;                                    \
    const float4 x0_ = *(const float4*)&x_lds[base_ + ((0 ^ sw_) << 2)];    \
    const float4 x1_ = *(const float4*)&x_lds[base_ + ((1 ^ sw_) << 2)];    \
    const float4 x2_ = *(const float4*)&x_lds[base_ + ((2 ^ sw_) << 2)];    \
    const float4 x3_ = *(const float4*)&x_lds[base_ + ((3 ^ sw_) << 2)];    \
    acc0.x = fmaf(c_, x0_.x, acc0.x); acc0.y = fmaf(c_, x0_.y, acc0.y);     \
    acc0.z = fmaf(c_, x0_.z, acc0.z); acc0.w = fmaf(c_, x0_.w, acc0.w);     \
    acc1.x = fmaf(c_, x1_.x, acc1.x); acc1.y = fmaf(c_, x1_.y, acc1.y);     \
    acc1.z = fmaf(c_, x1_.z, acc1.z); acc1.w = fmaf(c_, x1_.w, acc1.w);     \
    acc2.x = fmaf(c_, x2_.x, acc2.x); acc2.y = fmaf(c_, x2_.y, acc2.y);     \
    acc2.z = fmaf(c_, x2_.z, acc2.z); acc2.w = fmaf(c_, x2_.w, acc2.w);     \
    acc3.x = fmaf(c_, x3_.x, acc3.x); acc3.y = fmaf(c_, x3_.y, acc3.y);     \
    acc3.z = fmaf(c_, x3_.z, acc3.z); acc3.w = fmaf(c_, x3_.w, acc3.w);     \
} while (0)

// Consume one 256-k step held in P0..P3.
#define COMPUTE(P0, P1, P2, P3, K0) do {                                    \
    const int kb_ = ((K0) & (PHASE_K - 1)) + lane;                          \
    STEP_J(P0.x, P1.x, P2.x, P3.x, kb_);                                    \
    STEP_J(P0.y, P1.y, P2.y, P3.y, kb_ + 64);                               \
    STEP_J(P0.z, P1.z, P2.z, P3.z, kb_ + 128);                              \
    STEP_J(P0.w, P1.w, P2.w, P3.w, kb_ + 192);                              \
} while (0)

#define RED4(A) do {                                                        \
    A.x += __shfl_xor(A.x, mask, 64); A.y += __shfl_xor(A.y, mask, 64);     \
    A.z += __shfl_xor(A.z, mask, 64); A.w += __shfl_xor(A.w, mask, 64);     \
} while (0)

__global__ __launch_bounds__(TPB) void diffconv_kernel(
    const float* __restrict__ X,      // [N, F]
    const float* __restrict__ theta,  // [3, 2]
    const float* __restrict__ Wp,     // [3, N, N]
    const float* __restrict__ WTp,    // [3, N, N]
    float* __restrict__ out)          // [N, F]
{
    __shared__ float x_lds[PHASE_K * F];   // 64 KB, quad-XOR swizzled

    const int tid  = threadIdx.x;
    const int lane = tid & 63;
    const int wave = tid >> 6;
    const int r    = blockIdx.x * RPB + wave;

    const float th00 = theta[0], th01 = theta[1];
    const float th10 = theta[2], th11 = theta[3];
    const float th20 = theta[4], th21 = theta[5];

    const float* __restrict__ Wp1  = Wp  + (size_t)N * N;
    const float* __restrict__ Wp2  = Wp  + 2 * (size_t)N * N;
    const float* __restrict__ WTp1 = WTp + (size_t)N * N;
    const float* __restrict__ WTp2 = WTp + 2 * (size_t)N * N;

    const size_t rowb = (size_t)r * N;

    float4 acc0 = {0,0,0,0}, acc1 = {0,0,0,0}, acc2 = {0,0,0,0}, acc3 = {0,0,0,0};
    float4 pa0, pa1, pa2, pa3;   // pipeline buffer A
    float4 pb0, pb1, pb2, pb3;   // pipeline buffer B

    PREFETCH(pa0, pa1, pa2, pa3, 0);   // overlaps with phase-0 staging

    for (int p = 0; p < 4; ++p) {
        __syncthreads();   // all waves done reading previous phase
        // Stage phase p: X rows [p*1024, p*1024+1024) -> swizzled LDS.
#pragma unroll
        for (int h = 0; h < 2; ++h) {
            const int krel = tid + h * 512;
            const float4* src =
                (const float4*)(X + (size_t)(p * PHASE_K + krel) * F);
            const int base = krel << 4;
            const int sw   = (krel >> 1) & 3;
            *(float4*)&x_lds[base + ((0 ^ sw) << 2)] = src[0];
            *(float4*)&x_lds[base + ((1 ^ sw) << 2)] = src[1];
            *(float4*)&x_lds[base + ((2 ^ sw) << 2)] = src[2];
            *(float4*)&x_lds[base + ((3 ^ sw) << 2)] = src[3];
        }
        __syncthreads();

        const int k0 = p * PHASE_K;
        // 4 steps of 256 k; prefetch next step before consuming current.
        PREFETCH(pb0, pb1, pb2, pb3, k0 + 256);
        COMPUTE (pa0, pa1, pa2, pa3, k0);
        PREFETCH(pa0, pa1, pa2, pa3, k0 + 512);
        COMPUTE (pb0, pb1, pb2, pb3, k0 + 256);
        PREFETCH(pb0, pb1, pb2, pb3, k0 + 768);
        COMPUTE (pa0, pa1, pa2, pa3, k0 + 512);
        if (p < 3) PREFETCH(pa0, pa1, pa2, pa3, k0 + 1024);  // next phase
        COMPUTE (pb0, pb1, pb2, pb3, k0 + 768);
    }

    // Butterfly-reduce the per-lane k-partials across the 64 lanes.
#pragma unroll
    for (int mask = 1; mask < 64; mask <<= 1) {
        RED4(acc0); RED4(acc1); RED4(acc2); RED4(acc3);
    }

    if (lane == 0) {
        const float self_scale = 1.0f + th00 + th01;
        const float4* xp = (const float4*)(X + (size_t)r * F);
        float4*       op = (float4*)(out + (size_t)r * F);
        float4 ov;
        float4 xv = xp[0];
        ov.x = self_scale*xv.x + acc0.x; ov.y = self_scale*xv.y + acc0.y;
        ov.z = self_scale*xv.z + acc0.z; ov.w = self_scale*xv.w + acc0.w;
        op[0] = ov;
        xv = xp[1];
        ov.x = self_scale*xv.x + acc1.x; ov.y = self_scale*xv.y + acc1.y;
        ov.z = self_scale*xv.z + acc1.z; ov.w = self_scale*xv.w + acc1.w;
        op[1] = ov;
        xv = xp[2];
        ov.x = self_scale*xv.x + acc2.x; ov.y = self_scale*xv.y + acc2.y;
        ov.z = self_scale*xv.z + acc2.z; ov.w = self_scale*xv.w + acc2.w;
        op[2] = ov;
        xv = xp[3];
        ov.x = self_scale*xv.x + acc3.x; ov.y = self_scale*xv.y + acc3.y;
        ov.z = self_scale*xv.z + acc3.z; ov.w = self_scale*xv.w + acc3.w;
        op[3] = ov;
    }
}

extern "C" void kernel_launch(void* const* d_in, const int* in_sizes, int n_in,
                              void* d_out, int out_size, void* d_ws, size_t ws_size,
                              hipStream_t stream) {
    const float* X     = (const float*)d_in[0];
    const float* theta = (const float*)d_in[1];
    const float* Wp    = (const float*)d_in[2];
    const float* WTp   = (const float*)d_in[3];
    float* out = (float*)d_out;

    diffconv_kernel<<<N / RPB, TPB, 0, stream>>>(X, theta, Wp, WTp, out);
}